// Round 13
// baseline (245.773 us; speedup 1.0000x reference)
//
#include <hip/hip_runtime.h>
#include <hip/hip_bf16.h>

// KGAT-style 2-hop relational graph attention on MI355X — round 20.
//
// vs round 19 (238.1 us): (a) depth-3 pipeline REVERTED (hop2 52->53.4
// regression; latency was already covered at depth 2); (b) prep+route merge
// kept but understood as neutral (memset is itself a stream op — dispatch
// count never dropped); (c) NEW: CSR-compacted edge payload.
//   The fixed-stride bucket (CAP=32 -> 128 B/head) cost 25.6 MB of FETCH
//   per hop to deliver 4.8 MB of real edges (~20 MB/hop padding, paid
//   twice). fill3s now prefix-sums its 500 LDS counts (thread-0 serial),
//   claims a contiguous region via ONE global atomicAdd per block, and
//   writes a compacted 4.8 MB edge array. order[] becomes uint2
//   {head|deg<<18, start} in the same stratified-transposed layout.
//   Per-head slot order and summation order unchanged -> absmax identical.
//
// dtypes: all float32 (reference), indices int32 (harness int64->int32).

#define N_ENT  200000
#define N_EDGE 1200000
#define N_REL  32
#define DIM    64
#define LEAKY  0.2f
#define CAP    32                                      // max slots per head
#define NBIN   (CAP + 1)                               // degree bins 0..32
#define SUBH   500                                     // heads per sub-band
#define NSUB   (N_ENT / SUBH)                          // 400 sub-bands
#define SQCAP  3500                                    // mean 3000 + 9.1 sigma
#define I4PB   2048                                    // int4-groups per route block (8192 edges)
#define NRB    ((N_EDGE / 4 + I4PB - 1) / I4PB)        // 147 route blocks

template <int CTRL>
__device__ __forceinline__ float dpp_add(float x) {
  int t = __builtin_amdgcn_update_dpp(0, __float_as_int(x), CTRL, 0xF, 0xF, true);
  return x + __int_as_float(t);
}
// 16-lane (DPP row) allreduce sum; result valid in all 16 lanes of the row.
__device__ __forceinline__ float red16(float x) {
  x = dpp_add<0xB1>(x);    // quad_perm [1,0,3,2]  (xor 1)
  x = dpp_add<0x4E>(x);    // quad_perm [2,3,0,1]  (xor 2)
  x = dpp_add<0x124>(x);   // row_ror:4
  x = dpp_add<0x128>(x);   // row_ror:8
  return x;
}

// 4 bf16 (as 2 uints, low/high packed) -> float4
__device__ __forceinline__ float4 unpack4(uint2 u) {
  float4 t;
  t.x = __uint_as_float(u.x << 16);
  t.y = __uint_as_float(u.x & 0xFFFF0000u);
  t.z = __uint_as_float(u.y << 16);
  t.w = __uint_as_float(u.y & 0xFFFF0000u);
  return t;
}
// two f32 -> packed bf16 pair (round-to-nearest-even)
__device__ __forceinline__ unsigned pk(float a, float b) {
  unsigned ua = __float_as_uint(a);
  ua += 0x7FFFu + ((ua >> 16) & 1u);
  unsigned ub = __float_as_uint(b);
  ub += 0x7FFFu + ((ub >> 16) & 1u);
  return (ua >> 16) | (ub & 0xFFFF0000u);
}

// preproute: every block does a prep stride-slice (Q + bf16 entity table);
// blocks 0..NRB-1 additionally route their 8192-edge tile into 400 queues
// (pass1 LDS histogram + one global atomicAdd per touched queue; pass2
// re-read tile (L2-hot) and scatter). sqcnt/ecnt zeroed by hipMemsetAsync.
__global__ __launch_bounds__(256) void preproute(
    const float* __restrict__ W, const float* __restrict__ R,
    float* __restrict__ Q,
    const float4* __restrict__ ent04, uint2* __restrict__ ent0b,
    const int4* __restrict__ head4, const int4* __restrict__ tail4,
    const int4* __restrict__ type4,
    int* __restrict__ sqcnt, uint2* __restrict__ sqdata) {
  __shared__ int lcnt[NSUB];
  __shared__ int lbase[NSUB];
  __shared__ int lrank[NSUB];
  // ---- route part (blocks 0..NRB-1) ----
  if (blockIdx.x < NRB) {
    for (int i = threadIdx.x; i < NSUB; i += blockDim.x) {
      lcnt[i] = 0;
      lrank[i] = 0;
    }
    __syncthreads();
    int base = blockIdx.x * I4PB;
    int lim = min(N_EDGE / 4, base + I4PB);
    for (int k = base + threadIdx.x; k < lim; k += blockDim.x) {
      int4 h = head4[k];
      atomicAdd(&lcnt[h.x / SUBH], 1);
      atomicAdd(&lcnt[h.y / SUBH], 1);
      atomicAdd(&lcnt[h.z / SUBH], 1);
      atomicAdd(&lcnt[h.w / SUBH], 1);
    }
    __syncthreads();
    for (int i = threadIdx.x; i < NSUB; i += blockDim.x)
      if (lcnt[i] > 0) lbase[i] = atomicAdd(&sqcnt[i], lcnt[i]);
    __syncthreads();
    for (int k = base + threadIdx.x; k < lim; k += blockDim.x) {
      int4 h = head4[k];
      int4 t = tail4[k];
      int4 r = type4[k];
      int s, p;
      s = h.x / SUBH; p = lbase[s] + atomicAdd(&lrank[s], 1);
      if (p < SQCAP) sqdata[(size_t)s * SQCAP + p] =
          make_uint2((unsigned)t.x | ((unsigned)r.x << 18), (unsigned)h.x);
      s = h.y / SUBH; p = lbase[s] + atomicAdd(&lrank[s], 1);
      if (p < SQCAP) sqdata[(size_t)s * SQCAP + p] =
          make_uint2((unsigned)t.y | ((unsigned)r.y << 18), (unsigned)h.y);
      s = h.z / SUBH; p = lbase[s] + atomicAdd(&lrank[s], 1);
      if (p < SQCAP) sqdata[(size_t)s * SQCAP + p] =
          make_uint2((unsigned)t.z | ((unsigned)r.z << 18), (unsigned)h.z);
      s = h.w / SUBH; p = lbase[s] + atomicAdd(&lrank[s], 1);
      if (p < SQCAP) sqdata[(size_t)s * SQCAP + p] =
          make_uint2((unsigned)t.w | ((unsigned)r.w << 18), (unsigned)h.w);
    }
  }
  // ---- prep part (all blocks) ----
  int tid = blockIdx.x * blockDim.x + threadIdx.x;
  int stride = gridDim.x * blockDim.x;
  for (int i = tid; i < N_REL * 2 * DIM; i += stride) {
    int r = i >> 7;
    int k = i & 127;
    float acc = 0.f;
#pragma unroll 8
    for (int j = 0; j < DIM; ++j)
      acc += W[k * DIM + j] * R[r * DIM + j];
    Q[i] = acc;
  }
  for (int i = tid; i < N_ENT * DIM / 4; i += stride) {
    float4 v = ent04[i];
    ent0b[i] = make_uint2(pk(v.x, v.y), pk(v.z, v.w));
  }
}

// fill3s: one block per sub-band. Bin ~3000 records into a 64 KB LDS staging
// bucket (LDS atomics), prefix-sum the 500 clamped counts, claim a
// contiguous region of the global CSR edge array with ONE atomicAdd, write
// the compacted edges (contiguous per block), then local degree sort ->
// transposed stratified order2[slot*NSUB+g] = {head|deg<<18, start}.
__global__ __launch_bounds__(256) void fill3s(
    const int* __restrict__ sqcnt,
    const uint2* __restrict__ sqdata,
    unsigned* __restrict__ edges,
    uint2* __restrict__ order2,
    int* __restrict__ ecnt) {
  __shared__ unsigned lbucket[SUBH * CAP];   // 64000 B staging
  __shared__ int lcur[SUBH];                 // 2000 B
  __shared__ int lpref[SUBH];                // 2000 B (exclusive prefix)
  __shared__ int lbin[NBIN];                 // 132 B
  __shared__ int lbs[NBIN];                  // 132 B
  __shared__ int lrk[NBIN];                  // 132 B
  __shared__ int gbase;
  int g = blockIdx.x;
  int hbase = g * SUBH;
  for (int i = threadIdx.x; i < SUBH; i += blockDim.x) lcur[i] = 0;
  if (threadIdx.x < NBIN) { lbin[threadIdx.x] = 0; lrk[threadIdx.x] = 0; }
  __syncthreads();
  int n = min(sqcnt[g], SQCAP);
  const uint2* q = sqdata + (size_t)g * SQCAP;
  for (int k = threadIdx.x; k < n; k += blockDim.x) {
    uint2 rec = q[k];
    int lh = (int)rec.y - hbase;             // 0..SUBH-1
    int p = atomicAdd(&lcur[lh], 1);
    if (p < CAP) lbucket[lh * CAP + p] = rec.x;
  }
  __syncthreads();
  // prefix of clamped counts + claim global CSR region
  if (threadIdx.x == 0) {
    int s = 0;
    for (int i = 0; i < SUBH; ++i) { lpref[i] = s; s += min(lcur[i], CAP); }
    gbase = atomicAdd(ecnt, s);
  }
  __syncthreads();
  // compacted edge writeout: thread i owns head i's run; runs are contiguous
  // across threads -> the union is one contiguous region (L2-coalesced).
  for (int i = threadIdx.x; i < SUBH; i += blockDim.x) {
    int d = min(lcur[i], CAP);
    int dst = gbase + lpref[i];
    for (int k = 0; k < d; ++k) edges[dst + k] = lbucket[i * CAP + k];
  }
  // local degree histogram -> scan -> transposed stratified order2
  for (int i = threadIdx.x; i < SUBH; i += blockDim.x)
    atomicAdd(&lbin[min(lcur[i], CAP)], 1);
  __syncthreads();
  if (threadIdx.x == 0) {
    int s = 0;
    for (int b = 0; b < NBIN; ++b) { lbs[b] = s; s += lbin[b]; }
  }
  __syncthreads();
  for (int i = threadIdx.x; i < SUBH; i += blockDim.x) {
    int d = min(lcur[i], CAP);
    int slot = lbs[d] + atomicAdd(&lrk[d], 1);
    order2[(size_t)slot * NSUB + g] =
        make_uint2((unsigned)(hbase + i) | ((unsigned)d << 18),
                   (unsigned)(gbase + lpref[i]));
  }
}

// persistent hop kernel: wave = 4 groups x 16 lanes, 4 heads/wave, heads from
// order2[] ({head|deg<<18, csr_start}; transposed-stratified -> quads are
// degree-uniform and wave totals balanced). All entity rows read as bf16
// (128 B = 1 line). Per-edge CSR broadcast loads (edges[] is 4.8 MB,
// mostly L2/L3-resident), depth-2 gather pipeline. Softmax un-maxed.
// HOP==1: heads/gather = ent0b, out = h1b (bf16)
// HOP==2: heads/gather = h1b, residual = ent0b + 0.5*eh, out f32
template <int HOP>
__global__ __launch_bounds__(256, 8) void hop_kernel(
    const ushort* __restrict__ entb,     // bf16 head/gather table
    const ushort* __restrict__ e0b,      // bf16 ent0 table (HOP2 residual)
    const float4* __restrict__ Qg,
    const uint2* __restrict__ order2,
    const unsigned* __restrict__ edges,
    uint2* __restrict__ outb,            // HOP1
    float* __restrict__ outf) {          // HOP2
  __shared__ float4 sQ[N_REL * 32];   // [r][half(2)][sub(16)]
  for (int i = threadIdx.x; i < N_REL * 32; i += blockDim.x) sQ[i] = Qg[i];
  __syncthreads();
  const int lane = threadIdx.x & 63;
  const int sub = lane & 15;
  const int grp = lane >> 4;
  const int wave = (blockIdx.x * blockDim.x + threadIdx.x) >> 6;
  const int nWaves = (gridDim.x * blockDim.x) >> 6;
  const uint2* gtab = (const uint2*)entb;
  for (int n4 = wave * 4; n4 < N_ENT; n4 += nWaves * 4) {
    uint2 oe = order2[n4 + grp];      // N_ENT % 4 == 0 -> always < N_ENT
    int n = (int)(oe.x & 0x3FFFFu);
    int len = (int)(oe.x >> 18);
    int b = (int)oe.y;                // CSR start
    float4 eh = unpack4(gtab[(size_t)n * 16 + sub]);
    float l = 0.f;
    float4 acc = make_float4(0.f, 0.f, 0.f, 0.f);
    // depth-2 software pipeline over the segment (predicated per group)
    unsigned p0 = 0u, p1 = 0u;
    uint2 t0 = make_uint2(0u, 0u), t1 = t0;
    if (0 < len) { p0 = edges[b];     t0 = gtab[(size_t)(p0 & 0x3FFFFu) * 16 + sub]; }
    if (1 < len) { p1 = edges[b + 1]; t1 = gtab[(size_t)(p1 & 0x3FFFFu) * 16 + sub]; }
    for (int i = 0; __any(i < len); ++i) {
      unsigned p2 = 0u;
      uint2 t2 = make_uint2(0u, 0u);
      if (i + 2 < len) { p2 = edges[b + i + 2];
                         t2 = gtab[(size_t)(p2 & 0x3FFFFu) * 16 + sub]; }
      if (i < len) {
        int r = (int)(p0 >> 18);
        float4 qh = sQ[r * 32 + sub];
        float4 qt = sQ[r * 32 + 16 + sub];
        float4 et = unpack4(t0);
        float d = eh.x * qh.x + eh.y * qh.y + eh.z * qh.z + eh.w * qh.w
                + et.x * qt.x + et.y * qt.y + et.z * qt.z + et.w * qt.w;
        d = red16(d);
        float v = d > 0.f ? d : LEAKY * d;
        float ex = __expf(v);
        l += ex;
        acc.x = fmaf(ex, et.x, acc.x);
        acc.y = fmaf(ex, et.y, acc.y);
        acc.z = fmaf(ex, et.z, acc.z);
        acc.w = fmaf(ex, et.w, acc.w);
      }
      p0 = p1; t0 = t1; p1 = p2; t1 = t2;
    }
    float inv = (l > 0.f) ? 1.f / l : 0.f;
    float4 v;
    v.x = fmaf(acc.x, inv, eh.x);
    v.y = fmaf(acc.y, inv, eh.y);
    v.z = fmaf(acc.z, inv, eh.z);
    v.w = fmaf(acc.w, inv, eh.w);
    float s = v.x * v.x + v.y * v.y + v.z * v.z + v.w * v.w;
    s = red16(s);
    float rn = 1.f / fmaxf(sqrtf(s), 1e-12f);
    if (HOP == 1) {
      outb[(size_t)n * 16 + sub] = make_uint2(pk(v.x * rn, v.y * rn),
                                              pk(v.z * rn, v.w * rn));
    } else {
      float4 e0 = unpack4(((const uint2*)e0b)[(size_t)n * 16 + sub]);
      float4 o;
      o.x = fmaf(0.25f, e0.x, fmaf(0.5f, eh.x, v.x * rn));
      o.y = fmaf(0.25f, e0.y, fmaf(0.5f, eh.y, v.y * rn));
      o.z = fmaf(0.25f, e0.z, fmaf(0.5f, eh.z, v.z * rn));
      o.w = fmaf(0.25f, e0.w, fmaf(0.5f, eh.w, v.w * rn));
      ((float4*)(outf + (size_t)n * DIM))[sub] = o;
    }
  }
}

extern "C" void kernel_launch(void* const* d_in, const int* in_sizes, int n_in,
                              void* d_out, int out_size, void* d_ws, size_t ws_size,
                              hipStream_t stream) {
  const float* ent0 = (const float*)d_in[0];
  const float* rel  = (const float*)d_in[1];
  const float* W    = (const float*)d_in[2];
  const int* edge_index = (const int*)d_in[3];
  const int* etype      = (const int*)d_in[4];
  const int* head = edge_index;            // edge_index[0, :]
  const int* tail = edge_index + N_EDGE;   // edge_index[1, :]
  float* out = (float*)d_out;

  // workspace (~57.6 MB): Q | edges(CSR) | ent0b | h1b | order2 | sqcnt+ecnt.
  // sqdata (400 x 3500 x 8 B = 11.2 MB) ALIASES h1b (dead until hop1).
  char* ws = (char*)d_ws;
  float*    Q      = (float*)ws;                              // 16384 B
  unsigned* edges  = (unsigned*)(ws + 16384);                 // 4.8 MB
  ushort*   ent0b  = (ushort*)(ws + 16384 + 4800000);         // 25.6 MB
  ushort*   h1b    = (ushort*)(ws + 16384 + 30400000);        // 25.6 MB
  uint2*    order2 = (uint2*)(ws + 16384 + 56000000);         // 1.6 MB
  int*      sqcnt  = (int*)(ws + 16384 + 57600000);           // 1600 B
  int*      ecnt   = (int*)(ws + 16384 + 57601600);           // 4 B
  uint2*    sqdata = (uint2*)h1b;                             // aliased

  // ---- pipeline: memset (sqcnt+ecnt) + 4 kernels ----
  hipMemsetAsync(sqcnt, 0, NSUB * sizeof(int) + 64, stream);
  preproute<<<2048, 256, 0, stream>>>(
      W, rel, Q, (const float4*)ent0, (uint2*)ent0b,
      (const int4*)head, (const int4*)tail, (const int4*)etype,
      sqcnt, sqdata);
  fill3s<<<NSUB, 256, 0, stream>>>(sqcnt, sqdata, edges, order2, ecnt);
  hop_kernel<1><<<2048, 256, 0, stream>>>(ent0b, nullptr, (const float4*)Q,
                                          order2, edges, (uint2*)h1b, nullptr);
  hop_kernel<2><<<2048, 256, 0, stream>>>(h1b, ent0b, (const float4*)Q,
                                          order2, edges, nullptr, out);
}